// Round 1
// baseline (65.201 us; speedup 1.0000x reference)
//
#include <hip/hip_runtime.h>
#include <hip/hip_bf16.h>
#include <math.h>

// Problem constants (from reference)
#define B_ 128
#define C_ 8
#define T_ 128
#define K_ 20
#define S_ 128

// ---------------------------------------------------------------------------
// Kernel 1: DTW distance per (b,k) pair, wavefront-pipelined across one wave.
// Lane l owns columns s0=2l, s1=2l+1. At step d, lane l processes row t=d-l.
// Left/diag neighbors come from lane l-1 via shfl_up (values from its previous
// step, i.e. exactly row t and t-1 of column 2l-1).
// ---------------------------------------------------------------------------
__global__ __launch_bounds__(64) void dtw_kernel(const float* __restrict__ x,
                                                 const float* __restrict__ bary,
                                                 const float* __restrict__ top_dist,
                                                 int* __restrict__ dtw_gt) {
    int pair = blockIdx.x;
    int b = pair / K_;
    int kk = pair - b * K_;
    int lane = threadIdx.x;

    __shared__ __align__(16) float xs[T_][C_];   // x[b] transposed to [t][c], 4KB

    // Stage x[b]: x layout is [B][C][T]; read coalesced over t, scatter to LDS.
    #pragma unroll
    for (int i = 0; i < (T_ * C_) / 64; ++i) {
        int idx = i * 64 + lane;
        int t = idx & (T_ - 1);
        int c = idx >> 7;
        xs[t][c] = x[(b * C_ + c) * T_ + t];
    }

    // Barycenter columns for this lane (16 floats, registers).
    float bv0[8], bv1[8];
    {
        const float4* bp = (const float4*)(bary + (size_t)(kk * S_ + 2 * lane) * C_);
        float4 a0 = bp[0], a1 = bp[1], a2 = bp[2], a3 = bp[3];
        bv0[0] = a0.x; bv0[1] = a0.y; bv0[2] = a0.z; bv0[3] = a0.w;
        bv0[4] = a1.x; bv0[5] = a1.y; bv0[6] = a1.z; bv0[7] = a1.w;
        bv1[0] = a2.x; bv1[1] = a2.y; bv1[2] = a2.z; bv1[3] = a2.w;
        bv1[4] = a3.x; bv1[5] = a3.y; bv1[6] = a3.z; bv1[7] = a3.w;
    }
    __syncthreads();

    const float INF = __builtin_inff();
    // State: c0,c1 = D[t-1][s0,s1] (last computed row), p0,p1 = D[t-2][s0,s1].
    float c0 = INF, c1 = INF, p0 = INF, p1 = INF;

    for (int d = 0; d < T_ + 63; ++d) {
        // Neighbor values from lane l-1's end-of-previous-step state:
        //   lc = D[t][s0-1] (lane l-1 just computed row t), lp = D[t-1][s0-1].
        float lc = __shfl_up(c1, 1);
        float lp = __shfl_up(p1, 1);
        int t = d - lane;
        if (t >= 0 && t < T_) {
            p0 = c0;      // now p = D[t-1][own cols]
            p1 = c1;
            // cost(t, s0/s1) = sum_c (x[t][c] - b[s][c])^2
            float4 xa = *(const float4*)&xs[t][0];
            float4 xb = *(const float4*)&xs[t][4];
            float xv[8];
            xv[0] = xa.x; xv[1] = xa.y; xv[2] = xa.z; xv[3] = xa.w;
            xv[4] = xb.x; xv[5] = xb.y; xv[6] = xb.z; xv[7] = xb.w;
            float cost0 = 0.0f, cost1 = 0.0f;
            #pragma unroll
            for (int ch = 0; ch < 8; ++ch) {
                float d0 = xv[ch] - bv0[ch];
                float d1 = xv[ch] - bv1[ch];
                cost0 = fmaf(d0, d0, cost0);
                cost1 = fmaf(d1, d1, cost1);
            }
            // Boundary conditions: virtual D[-1][-1]=0, D[-1][s]=inf, D[t][-1]=inf.
            float up0 = (t == 0) ? INF : p0;
            float up1 = (t == 0) ? INF : p1;
            float dg1 = (t == 0) ? INF : p0;
            float dg0, lf0;
            if (lane == 0) {
                dg0 = (t == 0) ? 0.0f : INF;
                lf0 = INF;
            } else {
                dg0 = (t == 0) ? INF : lp;
                lf0 = lc;
            }
            c0 = cost0 + fminf(fminf(up0, dg0), lf0);
            c1 = cost1 + fminf(fminf(up1, dg1), c0);
        }
    }

    if (lane == 63) {
        // c1 = D[T-1][S-1] = accumulated DTW cost
        dtw_gt[pair] = (logf(c1) > top_dist[kk]) ? 1 : 0;
    }
}

// ---------------------------------------------------------------------------
// Kernel 2: full cross-correlation max per (b,k,c), then
// cc_fail[b,k] = any_c( max_lag cc <= bottom_cc[k,c] ).
// Block = one (b,k) pair, 256 threads = 8 channel-groups of 32 lanes.
// Lane owns 8 consecutive lags; x zero-padded in LDS so the 128-step MAC loop
// has no bounds checks; 12-register sliding window -> 1 float4 LDS read / 4 steps.
// ---------------------------------------------------------------------------
#define CC_ROW 396   // padded row stride in floats (>= 388, %4==0, breaks bank overlap)

__global__ __launch_bounds__(256) void cc_kernel(const float* __restrict__ x,
                                                 const float* __restrict__ bary,
                                                 const float* __restrict__ bottom_cc,
                                                 int* __restrict__ cc_fail) {
    int pair = blockIdx.x;
    int b = pair / K_;
    int kk = pair - b * K_;
    int tid = threadIdx.x;

    __shared__ __align__(16) float xp[C_ * CC_ROW];  // zero-padded x rows, ~12.4KB
    __shared__ __align__(16) float bt[C_][S_];       // barycenter transposed, 4KB
    __shared__ int fail;

    if (tid == 0) fail = 0;

    // Fill padded x: xp[c][j] = x[b,c,j-127] for j-127 in [0,T), else 0.
    for (int i = tid; i < C_ * CC_ROW; i += 256) {
        int c = i / CC_ROW;
        int j = i - c * CC_ROW;
        int t = j - (S_ - 1);
        float v = 0.0f;
        if (t >= 0 && t < T_) v = x[(b * C_ + c) * T_ + t];
        xp[i] = v;
    }
    // Transpose barycenter to [c][s].
    for (int i = tid; i < C_ * S_; i += 256) {
        int s = i >> 3;
        int c = i & 7;
        bt[c][s] = bary[(kk * S_ + s) * C_ + c];
    }
    __syncthreads();

    int c = tid >> 5;        // channel group
    int l = tid & 31;        // lane within group
    int lag0 = l * 8;        // 8 consecutive lags per lane: lag0..lag0+7 (0..255)
    const float* xr = &xp[c * CC_ROW];

    // Sliding window w[0..11] = xp[lag0+s .. lag0+s+11] at s-group start.
    float w[12];
    #pragma unroll
    for (int i = 0; i < 12; i += 4) {
        float4 v4 = *(const float4*)(xr + lag0 + i);
        w[i] = v4.x; w[i + 1] = v4.y; w[i + 2] = v4.z; w[i + 3] = v4.w;
    }
    float acc[8] = {0.f, 0.f, 0.f, 0.f, 0.f, 0.f, 0.f, 0.f};

    for (int s4 = 0; s4 < S_; s4 += 4) {
        #pragma unroll
        for (int u = 0; u < 4; ++u) {
            float bval = bt[c][s4 + u];   // broadcast read, conflict-free
            #pragma unroll
            for (int j = 0; j < 8; ++j)
                acc[j] = fmaf(w[u + j], bval, acc[j]);
        }
        // Slide window by 4, fetch next 4 (aligned float4; max idx 387 < 396).
        #pragma unroll
        for (int i = 0; i < 8; ++i) w[i] = w[i + 4];
        float4 v4 = *(const float4*)(xr + lag0 + s4 + 12);
        w[8] = v4.x; w[9] = v4.y; w[10] = v4.z; w[11] = v4.w;
    }

    // Lag 255 doesn't exist (only 0..254) -> mask before the max.
    if (l == 31) acc[7] = -__builtin_inff();
    float m = acc[0];
    #pragma unroll
    for (int j = 1; j < 8; ++j) m = fmaxf(m, acc[j]);
    #pragma unroll
    for (int off = 16; off > 0; off >>= 1)
        m = fmaxf(m, __shfl_xor(m, off));

    if (l == 0) {
        if (m <= bottom_cc[kk * C_ + c]) atomicOr(&fail, 1);
    }
    __syncthreads();
    if (tid == 0) cc_fail[pair] = fail;
}

// ---------------------------------------------------------------------------
// Kernel 3: combine flags -> output int32 labels.
// ---------------------------------------------------------------------------
__global__ void final_kernel(const int* __restrict__ preds,
                             const int* __restrict__ dtw_gt,
                             const int* __restrict__ cc_fail,
                             int* __restrict__ out) {
    int b = threadIdx.x;
    if (b < B_) {
        int dtw_all = 1, cc_all = 1;
        #pragma unroll
        for (int k = 0; k < K_; ++k) {
            dtw_all &= dtw_gt[b * K_ + k];
            cc_all &= cc_fail[b * K_ + k];
        }
        out[b] = (dtw_all | cc_all) ? K_ : preds[b];
    }
}

extern "C" void kernel_launch(void* const* d_in, const int* in_sizes, int n_in,
                              void* d_out, int out_size, void* d_ws, size_t ws_size,
                              hipStream_t stream) {
    const float* x         = (const float*)d_in[0];  // [B, C, T]
    const int*   preds     = (const int*)d_in[1];    // [B]
    const float* bary      = (const float*)d_in[2];  // [K, S, C]
    const float* top_dist  = (const float*)d_in[3];  // [K]
    const float* bottom_cc = (const float*)d_in[4];  // [K, C]
    int* out = (int*)d_out;                          // [B] int32

    int* dtw_gt  = (int*)d_ws;           // [B*K]
    int* cc_fail = dtw_gt + B_ * K_;     // [B*K]

    dtw_kernel<<<B_ * K_, 64, 0, stream>>>(x, bary, top_dist, dtw_gt);
    cc_kernel<<<B_ * K_, 256, 0, stream>>>(x, bary, bottom_cc, cc_fail);
    final_kernel<<<1, 128, 0, stream>>>(preds, dtw_gt, cc_fail, out);
}